// Round 3
// baseline (2259.470 us; speedup 1.0000x reference)
//
#include <hip/hip_runtime.h>
#include <hip/hip_bf16.h>
#include <cstddef>

// ---------------- zero fill (graph-capture-safe memset) ----------------

__global__ void k_zero(float4* __restrict__ p, long long total4) {
    long long i = (long long)blockIdx.x * blockDim.x + threadIdx.x;
    long long stride = (long long)gridDim.x * blockDim.x;
    for (; i < total4; i += stride) p[i] = make_float4(0.f, 0.f, 0.f, 0.f);
}

// ---------------- degree / norm ----------------

__global__ void k_deg(const int* __restrict__ dst, float* __restrict__ deg, int E) {
    int e = blockIdx.x * blockDim.x + threadIdx.x;
    if (e < E) atomicAdd(&deg[dst[e]], 1.0f);
}

__global__ void k_dinv(const float* __restrict__ deg, float* __restrict__ dinv, int N) {
    int i = blockIdx.x * blockDim.x + threadIdx.x;
    if (i < N) dinv[i] = rsqrtf(deg[i] + 1.0f);
}

// ---------------- tiled fp32 GEMM ----------------
// C[M,N] = A[M,K] @ B[K,N] (+bias). K must be a multiple of BK.

template<int BM, int BN, int BK, int TM, int TN>
__launch_bounds__(256)
__global__ void gemm_f32(const float* __restrict__ A, const float* __restrict__ B,
                         const float* __restrict__ bias, float* __restrict__ C,
                         int M, int N, int K)
{
    constexpr int TX = BN / TN;
    constexpr int TY = BM / TM;
    static_assert(TX * TY == 256, "need 256 threads");
    __shared__ float As[BK * (BM + 1)];   // transposed: As[k][m], +1 pad kills write conflicts
    __shared__ float Bs[BK * BN];         // natural:    Bs[k][n]

    const int tid = threadIdx.x;
    const int tx = tid % TX, ty = tid / TX;
    const int m0 = blockIdx.x * BM;
    const int n0 = blockIdx.y * BN;

    float acc[TM][TN];
#pragma unroll
    for (int i = 0; i < TM; ++i)
#pragma unroll
        for (int j = 0; j < TN; ++j) acc[i][j] = 0.0f;

    constexpr int AC4 = BK / 4;          // float4 slots per A row
    constexpr int AROWS = 256 / AC4;     // A rows loaded per pass
    const int a_c4 = tid % AC4, a_r = tid / AC4;

    constexpr int BC4 = BN / 4;
    constexpr int BROWS = 256 / BC4;
    const int b_c4 = tid % BC4, b_r = tid / BC4;

    for (int k0 = 0; k0 < K; k0 += BK) {
        // ---- stage A tile (transposed into LDS) ----
#pragma unroll
        for (int p = 0; p < BM / AROWS; ++p) {
            int row = a_r + p * AROWS;
            int gr = m0 + row;
            float4 v = make_float4(0.f, 0.f, 0.f, 0.f);
            if (gr < M) v = *(const float4*)(A + (size_t)gr * K + k0 + 4 * a_c4);
            As[(4 * a_c4 + 0) * (BM + 1) + row] = v.x;
            As[(4 * a_c4 + 1) * (BM + 1) + row] = v.y;
            As[(4 * a_c4 + 2) * (BM + 1) + row] = v.z;
            As[(4 * a_c4 + 3) * (BM + 1) + row] = v.w;
        }
        // ---- stage B tile ----
#pragma unroll
        for (int p = 0; p < BK / BROWS; ++p) {
            int row = b_r + p * BROWS;       // k within tile
            int gk = k0 + row;
            int gc = n0 + 4 * b_c4;
            float4 v = make_float4(0.f, 0.f, 0.f, 0.f);
            if (gc + 3 < N) {
                v = *(const float4*)(B + (size_t)gk * N + gc);
            } else {
                float t0 = (gc + 0 < N) ? B[(size_t)gk * N + gc + 0] : 0.f;
                float t1 = (gc + 1 < N) ? B[(size_t)gk * N + gc + 1] : 0.f;
                float t2 = (gc + 2 < N) ? B[(size_t)gk * N + gc + 2] : 0.f;
                float t3 = (gc + 3 < N) ? B[(size_t)gk * N + gc + 3] : 0.f;
                v = make_float4(t0, t1, t2, t3);
            }
            *(float4*)&Bs[row * BN + 4 * b_c4] = v;
        }
        __syncthreads();

#pragma unroll 8
        for (int kk = 0; kk < BK; ++kk) {
            float a[TM], b[TN];
#pragma unroll
            for (int i = 0; i < TM; ++i) a[i] = As[kk * (BM + 1) + ty * TM + i];
#pragma unroll
            for (int j = 0; j < TN; ++j) b[j] = Bs[kk * BN + tx * TN + j];
#pragma unroll
            for (int i = 0; i < TM; ++i)
#pragma unroll
                for (int j = 0; j < TN; ++j)
                    acc[i][j] = fmaf(a[i], b[j], acc[i][j]);
        }
        __syncthreads();
    }

#pragma unroll
    for (int i = 0; i < TM; ++i) {
        int gr = m0 + ty * TM + i;
        if (gr >= M) continue;
#pragma unroll
        for (int j = 0; j < TN; ++j) {
            int gc = n0 + tx * TN + j;
            if (gc >= N) continue;
            float v = acc[i][j];
            if (bias) v += bias[gc];
            C[(size_t)gr * N + gc] = v;
        }
    }
}

// ---------------- edge aggregation (atomic scatter) ----------------
// agg[dst] += h[src] * dinv[src]*dinv[dst], one wave per edge.

template<int F>
__global__ void k_agg(const float* __restrict__ h, const int* __restrict__ src,
                      const int* __restrict__ dst, const float* __restrict__ dinv,
                      float* __restrict__ agg, int E)
{
    int e = blockIdx.x * (blockDim.x / 64) + (threadIdx.x >> 6);
    int lane = threadIdx.x & 63;
    if (e >= E) return;
    int s = src[e];
    int d = dst[e];
    float w = dinv[s] * dinv[d];
    if (F == 128) {
        float2 v = *(const float2*)(h + (size_t)s * 128 + lane * 2);
        atomicAdd(agg + (size_t)d * 128 + lane * 2 + 0, v.x * w);
        atomicAdd(agg + (size_t)d * 128 + lane * 2 + 1, v.y * w);
    } else {
        float v = h[(size_t)s * 64 + lane];
        atomicAdd(agg + (size_t)d * 64 + lane, v * w);
    }
}

// ---------------- self-loop + bias + relu ----------------
// out = relu(agg + h*dinv^2 + bias), vectorized float4; out may alias agg.

template<int F>
__global__ void k_self_bias_relu(const float4* __restrict__ agg, const float4* __restrict__ h,
                                 const float* __restrict__ dinv, const float* __restrict__ bias,
                                 float4* __restrict__ out, int total4)
{
    int idx = blockIdx.x * blockDim.x + threadIdx.x;
    if (idx >= total4) return;
    constexpr int F4 = F / 4;
    int node = idx / F4;
    int f4 = idx % F4;
    float di = dinv[node];
    float w = di * di;
    float4 a = agg[idx];
    float4 hv = h[idx];
    float4 r;
    r.x = fmaxf(fmaf(hv.x, w, a.x) + bias[f4 * 4 + 0], 0.f);
    r.y = fmaxf(fmaf(hv.y, w, a.y) + bias[f4 * 4 + 1], 0.f);
    r.z = fmaxf(fmaf(hv.z, w, a.z) + bias[f4 * 4 + 2], 0.f);
    r.w = fmaxf(fmaf(hv.w, w, a.w) + bias[f4 * 4 + 3], 0.f);
    out[idx] = r;
}

// ---------------- launch ----------------
// NOTE: harness passes integer inputs as int32 (edge_index arrives as int*).
// Scratch plan (ws_size may be small, so big intermediates live inside d_out,
// which is N*1000 floats = 400 MB and fully overwritten by the final GEMM):
//   d_ws:  [deg 0.5MB][dinv 0.5MB][h2 25.6MB]                (~26.6 MB used)
//   d_out: [O0: h (51.2MB) -> h2pre (25.6MB)][O1: agg1/h1 (51.2MB)][O2: agg2 (25.6MB)]
//          all dead before final GEMM writes the full 400 MB.

extern "C" void kernel_launch(void* const* d_in, const int* in_sizes, int n_in,
                              void* d_out, int out_size, void* d_ws, size_t ws_size,
                              hipStream_t stream)
{
    const float* x   = (const float*)d_in[0];
    const float* W1  = (const float*)d_in[1];
    const float* b1  = (const float*)d_in[2];
    const float* W2  = (const float*)d_in[3];
    const float* b2  = (const float*)d_in[4];
    const float* Wfc = (const float*)d_in[5];
    const float* bfc = (const float*)d_in[6];
    const int*   ei  = (const int*)d_in[7];     // int32 in the harness!

    const int N = in_sizes[0] / 128;       // 100000
    const int E = in_sizes[7] / 2;         // 1600000
    const int* src = ei;
    const int* dst = ei + E;

    char* ws = (char*)d_ws;
    float* deg  = (float*)(ws);                       // N floats
    float* dinv = (float*)(ws + 512 * 1024);          // N floats
    float* h2   = (float*)(ws + 1024 * 1024);         // N*64 floats (25.6 MB)

    float* out = (float*)d_out;
    float* O0 = out;                                  // h [N,128] then h2pre [N,64]
    float* O1 = out + (size_t)N * 128;                // agg1/h1 [N,128]
    float* O2 = out + (size_t)N * 256;                // agg2 [N,64]

    // degree + dinv
    k_zero<<<64, 256, 0, stream>>>((float4*)deg, N / 4);
    k_deg<<<(E + 255) / 256, 256, 0, stream>>>(dst, deg, E);
    k_dinv<<<(N + 255) / 256, 256, 0, stream>>>(deg, dinv, N);

    // h = x @ W1   [N,128] -> O0
    {
        dim3 grid((N + 127) / 128, 1);
        gemm_f32<128, 128, 32, 8, 8><<<grid, 256, 0, stream>>>(x, W1, nullptr, O0, N, 128, 128);
    }

    // agg1 = scatter(h*norm) -> O1
    k_zero<<<2048, 256, 0, stream>>>((float4*)O1, (long long)N * 128 / 4);
    k_agg<128><<<(E + 3) / 4, 256, 0, stream>>>(O0, src, dst, dinv, O1, E);

    // h1 = relu(agg1 + h*dinv^2 + b1)  (in-place at O1)
    {
        int total4 = N * 128 / 4;
        k_self_bias_relu<128><<<(total4 + 255) / 256, 256, 0, stream>>>(
            (const float4*)O1, (const float4*)O0, dinv, b1, (float4*)O1, total4);
    }

    // h2pre = h1 @ W2   [N,64] -> O0 (h is dead)
    {
        dim3 grid((N + 127) / 128, 1);
        gemm_f32<128, 64, 32, 8, 4><<<grid, 256, 0, stream>>>(O1, W2, nullptr, O0, N, 64, 128);
    }

    // agg2 = scatter(h2pre*norm) -> O2
    k_zero<<<1024, 256, 0, stream>>>((float4*)O2, (long long)N * 64 / 4);
    k_agg<64><<<(E + 3) / 4, 256, 0, stream>>>(O0, src, dst, dinv, O2, E);

    // h2 = relu(agg2 + h2pre*dinv^2 + b2) -> ws (must survive final GEMM's d_out writes)
    {
        int total4 = N * 64 / 4;
        k_self_bias_relu<64><<<(total4 + 255) / 256, 256, 0, stream>>>(
            (const float4*)O2, (const float4*)O0, dinv, b2, (float4*)h2, total4);
    }

    // out = h2 @ Wfc + bfc   [N,1000] (overwrites all of d_out)
    {
        dim3 grid((N + 127) / 128, (1000 + 127) / 128);
        gemm_f32<128, 128, 32, 8, 8><<<grid, 256, 0, stream>>>(h2, Wfc, bfc, out, N, 1000, 64);
    }
}

// Round 4
// 920.395 us; speedup vs baseline: 2.4549x; 2.4549x over previous
//
#include <hip/hip_runtime.h>
#include <hip/hip_bf16.h>
#include <cstddef>

// ---------------- zero fill (graph-capture-safe memset) ----------------

__global__ void k_zero_i(int* __restrict__ p, int total) {
    int i = blockIdx.x * blockDim.x + threadIdx.x;
    int stride = gridDim.x * blockDim.x;
    for (; i < total; i += stride) p[i] = 0;
}

// ---------------- degree / norm ----------------

__global__ void k_deg_i(const int* __restrict__ dst, int* __restrict__ deg, int E) {
    int e = blockIdx.x * blockDim.x + threadIdx.x;
    if (e < E) atomicAdd(&deg[dst[e]], 1);
}

__global__ void k_dinv(const int* __restrict__ deg, float* __restrict__ dinv, int N) {
    int i = blockIdx.x * blockDim.x + threadIdx.x;
    if (i < N) dinv[i] = rsqrtf((float)deg[i] + 1.0f);
}

// ---------------- exclusive scan (3-phase, N <= 1024*1024) ----------------

#define SCAN_B 1024

__global__ void k_scan1(const int* __restrict__ in, int* __restrict__ out,
                        int* __restrict__ sums, int n) {
    __shared__ int tmp[SCAN_B];
    int tid = threadIdx.x;
    int gid = blockIdx.x * SCAN_B + tid;
    int v = (gid < n) ? in[gid] : 0;
    tmp[tid] = v;
    __syncthreads();
    for (int off = 1; off < SCAN_B; off <<= 1) {
        int t = (tid >= off) ? tmp[tid - off] : 0;
        __syncthreads();
        tmp[tid] += t;
        __syncthreads();
    }
    if (gid < n) out[gid] = tmp[tid] - v;          // exclusive
    if (tid == SCAN_B - 1) sums[blockIdx.x] = tmp[tid];
}

__global__ void k_scan2(int* __restrict__ sums, int nb) {
    __shared__ int tmp[128];
    int tid = threadIdx.x;
    int v = (tid < nb) ? sums[tid] : 0;
    tmp[tid] = v;
    __syncthreads();
    for (int off = 1; off < 128; off <<= 1) {
        int t = (tid >= off) ? tmp[tid - off] : 0;
        __syncthreads();
        tmp[tid] += t;
        __syncthreads();
    }
    if (tid < nb) sums[tid] = tmp[tid] - v;        // exclusive block offsets
}

__global__ void k_scan3(int* __restrict__ out, int* __restrict__ cursor,
                        const int* __restrict__ sums, int n) {
    int gid = blockIdx.x * SCAN_B + threadIdx.x;
    if (gid < n) {
        int v = out[gid] + sums[blockIdx.x];
        out[gid] = v;
        cursor[gid] = v;
    }
}

// ---------------- CSR fill ----------------

__global__ void k_fill(const int* __restrict__ src, const int* __restrict__ dst,
                       int* __restrict__ cursor, int* __restrict__ csr_src, int E) {
    int e = blockIdx.x * blockDim.x + threadIdx.x;
    if (e < E) {
        int pos = atomicAdd(&cursor[dst[e]], 1);
        csr_src[pos] = src[e];
    }
}

// ---------------- fused gather aggregation + self-loop + bias + relu ----------
// out[n] = relu( sum_{s in in(n)} h[s]*dinv[s]*dinv[n] + h[n]*dinv[n]^2 + bias )
// One wave per node; F=128 -> 2 floats/lane, F=64 -> 1 float/lane.

template<int F>
__launch_bounds__(256)
__global__ void k_gather(const float* __restrict__ h, const int* __restrict__ csr_src,
                         const int* __restrict__ off, const float* __restrict__ dinv,
                         const float* __restrict__ bias, float* __restrict__ out,
                         int N, int E)
{
    int node = blockIdx.x * (blockDim.x / 64) + (threadIdx.x >> 6);
    int lane = threadIdx.x & 63;
    if (node >= N) return;
    float dn = dinv[node];
    int beg = off[node];
    int end = (node + 1 < N) ? off[node + 1] : E;

    if (F == 128) {
        float ax = 0.f, ay = 0.f;
        int i = beg;
        for (; i + 1 < end; i += 2) {
            int s0 = csr_src[i];
            int s1 = csr_src[i + 1];
            float w0 = dinv[s0] * dn;
            float w1 = dinv[s1] * dn;
            float2 v0 = *(const float2*)(h + (size_t)s0 * 128 + lane * 2);
            float2 v1 = *(const float2*)(h + (size_t)s1 * 128 + lane * 2);
            ax += v0.x * w0 + v1.x * w1;
            ay += v0.y * w0 + v1.y * w1;
        }
        if (i < end) {
            int s = csr_src[i];
            float w = dinv[s] * dn;
            float2 v = *(const float2*)(h + (size_t)s * 128 + lane * 2);
            ax += v.x * w;
            ay += v.y * w;
        }
        float2 hv = *(const float2*)(h + (size_t)node * 128 + lane * 2);
        float w = dn * dn;
        ax = fmaxf(ax + hv.x * w + bias[lane * 2 + 0], 0.f);
        ay = fmaxf(ay + hv.y * w + bias[lane * 2 + 1], 0.f);
        *(float2*)(out + (size_t)node * 128 + lane * 2) = make_float2(ax, ay);
    } else {
        float a = 0.f;
        int i = beg;
        for (; i + 1 < end; i += 2) {
            int s0 = csr_src[i];
            int s1 = csr_src[i + 1];
            float w0 = dinv[s0] * dn;
            float w1 = dinv[s1] * dn;
            a += h[(size_t)s0 * 64 + lane] * w0 + h[(size_t)s1 * 64 + lane] * w1;
        }
        if (i < end) {
            int s = csr_src[i];
            a += h[(size_t)s * 64 + lane] * dinv[s] * dn;
        }
        a += h[(size_t)node * 64 + lane] * dn * dn + bias[lane];
        out[(size_t)node * 64 + lane] = fmaxf(a, 0.f);
    }
}

// ---------------- tiled fp32 GEMM ----------------
// C[M,N] = A[M,K] @ B[K,N] (+bias). K must be a multiple of BK.

template<int BM, int BN, int BK, int TM, int TN>
__launch_bounds__(256)
__global__ void gemm_f32(const float* __restrict__ A, const float* __restrict__ B,
                         const float* __restrict__ bias, float* __restrict__ C,
                         int M, int N, int K)
{
    constexpr int TX = BN / TN;
    constexpr int TY = BM / TM;
    static_assert(TX * TY == 256, "need 256 threads");
    __shared__ float As[BK * (BM + 1)];
    __shared__ float Bs[BK * BN];

    const int tid = threadIdx.x;
    const int tx = tid % TX, ty = tid / TX;
    const int m0 = blockIdx.x * BM;
    const int n0 = blockIdx.y * BN;

    float acc[TM][TN];
#pragma unroll
    for (int i = 0; i < TM; ++i)
#pragma unroll
        for (int j = 0; j < TN; ++j) acc[i][j] = 0.0f;

    constexpr int AC4 = BK / 4;
    constexpr int AROWS = 256 / AC4;
    const int a_c4 = tid % AC4, a_r = tid / AC4;

    constexpr int BC4 = BN / 4;
    constexpr int BROWS = 256 / BC4;
    const int b_c4 = tid % BC4, b_r = tid / BC4;

    for (int k0 = 0; k0 < K; k0 += BK) {
#pragma unroll
        for (int p = 0; p < BM / AROWS; ++p) {
            int row = a_r + p * AROWS;
            int gr = m0 + row;
            float4 v = make_float4(0.f, 0.f, 0.f, 0.f);
            if (gr < M) v = *(const float4*)(A + (size_t)gr * K + k0 + 4 * a_c4);
            As[(4 * a_c4 + 0) * (BM + 1) + row] = v.x;
            As[(4 * a_c4 + 1) * (BM + 1) + row] = v.y;
            As[(4 * a_c4 + 2) * (BM + 1) + row] = v.z;
            As[(4 * a_c4 + 3) * (BM + 1) + row] = v.w;
        }
#pragma unroll
        for (int p = 0; p < BK / BROWS; ++p) {
            int row = b_r + p * BROWS;
            int gk = k0 + row;
            int gc = n0 + 4 * b_c4;
            float4 v = make_float4(0.f, 0.f, 0.f, 0.f);
            if (gc + 3 < N) {
                v = *(const float4*)(B + (size_t)gk * N + gc);
            } else {
                float t0 = (gc + 0 < N) ? B[(size_t)gk * N + gc + 0] : 0.f;
                float t1 = (gc + 1 < N) ? B[(size_t)gk * N + gc + 1] : 0.f;
                float t2 = (gc + 2 < N) ? B[(size_t)gk * N + gc + 2] : 0.f;
                float t3 = (gc + 3 < N) ? B[(size_t)gk * N + gc + 3] : 0.f;
                v = make_float4(t0, t1, t2, t3);
            }
            *(float4*)&Bs[row * BN + 4 * b_c4] = v;
        }
        __syncthreads();

#pragma unroll 8
        for (int kk = 0; kk < BK; ++kk) {
            float a[TM], b[TN];
#pragma unroll
            for (int i = 0; i < TM; ++i) a[i] = As[kk * (BM + 1) + ty * TM + i];
#pragma unroll
            for (int j = 0; j < TN; ++j) b[j] = Bs[kk * BN + tx * TN + j];
#pragma unroll
            for (int i = 0; i < TM; ++i)
#pragma unroll
                for (int j = 0; j < TN; ++j)
                    acc[i][j] = fmaf(a[i], b[j], acc[i][j]);
        }
        __syncthreads();
    }

#pragma unroll
    for (int i = 0; i < TM; ++i) {
        int gr = m0 + ty * TM + i;
        if (gr >= M) continue;
#pragma unroll
        for (int j = 0; j < TN; ++j) {
            int gc = n0 + tx * TN + j;
            if (gc >= N) continue;
            float v = acc[i][j];
            if (bias) v += bias[gc];
            C[(size_t)gr * N + gc] = v;
        }
    }
}

// ---------------- launch ----------------
// Harness passes integer inputs as int32. d_out (400 MB) doubles as scratch:
//   O0 h[N,128] | O1 h1[N,128] | O2 h2pre[N,64] | O3 csr_src[E] | O4 offsets[N]
//   O5 cursor[N] | O6 deg_cnt[N] | O7 blockSums[128]     (all dead before final GEMM)
// d_ws: [dinv 0.5MB][h2 25.6MB] — h2 must survive the final GEMM's d_out writes.

extern "C" void kernel_launch(void* const* d_in, const int* in_sizes, int n_in,
                              void* d_out, int out_size, void* d_ws, size_t ws_size,
                              hipStream_t stream)
{
    const float* x   = (const float*)d_in[0];
    const float* W1  = (const float*)d_in[1];
    const float* b1  = (const float*)d_in[2];
    const float* W2  = (const float*)d_in[3];
    const float* b2  = (const float*)d_in[4];
    const float* Wfc = (const float*)d_in[5];
    const float* bfc = (const float*)d_in[6];
    const int*   ei  = (const int*)d_in[7];     // int32 in the harness

    const int N = in_sizes[0] / 128;       // 100000
    const int E = in_sizes[7] / 2;         // 1600000
    const int* src = ei;
    const int* dst = ei + E;

    char* ws = (char*)d_ws;
    float* dinv = (float*)(ws);                        // N floats
    float* h2   = (float*)(ws + 512 * 1024);           // N*64 floats (25.6 MB)

    float* out = (float*)d_out;
    float* O0      = out;                              // h [N,128], later h2pre source slot unused
    float* O1      = out + (size_t)N * 128;            // h1 [N,128]
    float* O2      = out + (size_t)N * 256;            // h2pre [N,64]
    int*   csr_src = (int*)(out + (size_t)N * 320);    // E ints (6.4 MB)
    int*   offs    = (int*)((char*)csr_src + (size_t)E * 4);          // N ints
    int*   cursor  = (int*)((char*)offs + (size_t)N * 4);             // N ints
    int*   deg_cnt = (int*)((char*)cursor + (size_t)N * 4);           // N ints
    int*   bsums   = (int*)((char*)deg_cnt + (size_t)N * 4);          // 128 ints

    const int nScanBlocks = (N + SCAN_B - 1) / SCAN_B;   // 98 <= 128

    // ---- degree, dinv, offsets, cursor ----
    k_zero_i<<<128, 256, 0, stream>>>(deg_cnt, N);
    k_deg_i<<<(E + 255) / 256, 256, 0, stream>>>(dst, deg_cnt, E);
    k_dinv<<<(N + 255) / 256, 256, 0, stream>>>(deg_cnt, dinv, N);
    k_scan1<<<nScanBlocks, SCAN_B, 0, stream>>>(deg_cnt, offs, bsums, N);
    k_scan2<<<1, 128, 0, stream>>>(bsums, nScanBlocks);
    k_scan3<<<nScanBlocks, SCAN_B, 0, stream>>>(offs, cursor, bsums, N);

    // ---- CSR fill ----
    k_fill<<<(E + 255) / 256, 256, 0, stream>>>(src, dst, cursor, csr_src, E);

    // ---- layer 1 ----
    // h = x @ W1 -> O0
    gemm_f32<128, 128, 32, 8, 8><<<dim3((N + 127) / 128, 1), 256, 0, stream>>>(
        x, W1, nullptr, O0, N, 128, 128);
    // h1 = relu(gather(h) + self + b1) -> O1
    k_gather<128><<<(N + 3) / 4, 256, 0, stream>>>(O0, csr_src, offs, dinv, b1, O1, N, E);

    // ---- layer 2 ----
    // h2pre = h1 @ W2 -> O2
    gemm_f32<128, 64, 32, 8, 4><<<dim3((N + 127) / 128, 1), 256, 0, stream>>>(
        O1, W2, nullptr, O2, N, 64, 128);
    // h2 = relu(gather(h2pre) + self + b2) -> ws
    k_gather<64><<<(N + 3) / 4, 256, 0, stream>>>(O2, csr_src, offs, dinv, b2, h2, N, E);

    // ---- output layer: out = h2 @ Wfc + bfc (overwrites all of d_out) ----
    gemm_f32<128, 128, 32, 8, 8><<<dim3((N + 127) / 128, (1000 + 127) / 128), 256, 0, stream>>>(
        h2, Wfc, bfc, out, N, 1000, 64);
}

// Round 5
// 836.534 us; speedup vs baseline: 2.7010x; 1.1002x over previous
//
#include <hip/hip_runtime.h>
#include <hip/hip_bf16.h>
#include <cstddef>

// ---------------- zero fill (graph-capture-safe memset) ----------------

__global__ void k_zero_i(int* __restrict__ p, int total) {
    int i = blockIdx.x * blockDim.x + threadIdx.x;
    int stride = gridDim.x * blockDim.x;
    for (; i < total; i += stride) p[i] = 0;
}

// ---------------- degree / norm ----------------

__global__ void k_deg_i(const int* __restrict__ dst, int* __restrict__ deg, int E) {
    int e = blockIdx.x * blockDim.x + threadIdx.x;
    if (e < E) atomicAdd(&deg[dst[e]], 1);
}

__global__ void k_dinv(const int* __restrict__ deg, float* __restrict__ dinv, int N) {
    int i = blockIdx.x * blockDim.x + threadIdx.x;
    if (i < N) dinv[i] = rsqrtf((float)deg[i] + 1.0f);
}

// ---------------- exclusive scan (3-phase, N <= 1024*1024) ----------------

#define SCAN_B 1024

__global__ void k_scan1(const int* __restrict__ in, int* __restrict__ out,
                        int* __restrict__ sums, int n) {
    __shared__ int tmp[SCAN_B];
    int tid = threadIdx.x;
    int gid = blockIdx.x * SCAN_B + tid;
    int v = (gid < n) ? in[gid] : 0;
    tmp[tid] = v;
    __syncthreads();
    for (int off = 1; off < SCAN_B; off <<= 1) {
        int t = (tid >= off) ? tmp[tid - off] : 0;
        __syncthreads();
        tmp[tid] += t;
        __syncthreads();
    }
    if (gid < n) out[gid] = tmp[tid] - v;          // exclusive
    if (tid == SCAN_B - 1) sums[blockIdx.x] = tmp[tid];
}

__global__ void k_scan2(int* __restrict__ sums, int nb) {
    __shared__ int tmp[128];
    int tid = threadIdx.x;
    int v = (tid < nb) ? sums[tid] : 0;
    tmp[tid] = v;
    __syncthreads();
    for (int off = 1; off < 128; off <<= 1) {
        int t = (tid >= off) ? tmp[tid - off] : 0;
        __syncthreads();
        tmp[tid] += t;
        __syncthreads();
    }
    if (tid < nb) sums[tid] = tmp[tid] - v;        // exclusive block offsets
}

__global__ void k_scan3(int* __restrict__ out, int* __restrict__ cursor,
                        const int* __restrict__ sums, int n) {
    int gid = blockIdx.x * SCAN_B + threadIdx.x;
    if (gid < n) {
        int v = out[gid] + sums[blockIdx.x];
        out[gid] = v;
        cursor[gid] = v;
    }
}

// ---------------- CSR fill ----------------

__global__ void k_fill(const int* __restrict__ src, const int* __restrict__ dst,
                       int* __restrict__ cursor, int* __restrict__ csr_src, int E) {
    int e = blockIdx.x * blockDim.x + threadIdx.x;
    if (e < E) {
        int pos = atomicAdd(&cursor[dst[e]], 1);
        csr_src[pos] = src[e];
    }
}

// ---------------- fused gather aggregation + self-loop + bias + relu ----------
// out[n] = relu( sum_{s in in(n)} h[s]*dinv[s]*dinv[n] + h[n]*dinv[n]^2 + bias )
// One wave per node; F=128 -> 2 floats/lane, F=64 -> 1 float/lane.

template<int F>
__launch_bounds__(256)
__global__ void k_gather(const float* __restrict__ h, const int* __restrict__ csr_src,
                         const int* __restrict__ off, const float* __restrict__ dinv,
                         const float* __restrict__ bias, float* __restrict__ out,
                         int N, int E)
{
    int node = blockIdx.x * (blockDim.x / 64) + (threadIdx.x >> 6);
    int lane = threadIdx.x & 63;
    if (node >= N) return;
    float dn = dinv[node];
    int beg = off[node];
    int end = (node + 1 < N) ? off[node + 1] : E;

    if (F == 128) {
        float ax = 0.f, ay = 0.f;
        int i = beg;
        for (; i + 1 < end; i += 2) {
            int s0 = csr_src[i];
            int s1 = csr_src[i + 1];
            float w0 = dinv[s0] * dn;
            float w1 = dinv[s1] * dn;
            float2 v0 = *(const float2*)(h + (size_t)s0 * 128 + lane * 2);
            float2 v1 = *(const float2*)(h + (size_t)s1 * 128 + lane * 2);
            ax += v0.x * w0 + v1.x * w1;
            ay += v0.y * w0 + v1.y * w1;
        }
        if (i < end) {
            int s = csr_src[i];
            float w = dinv[s] * dn;
            float2 v = *(const float2*)(h + (size_t)s * 128 + lane * 2);
            ax += v.x * w;
            ay += v.y * w;
        }
        float2 hv = *(const float2*)(h + (size_t)node * 128 + lane * 2);
        float w = dn * dn;
        ax = fmaxf(ax + hv.x * w + bias[lane * 2 + 0], 0.f);
        ay = fmaxf(ay + hv.y * w + bias[lane * 2 + 1], 0.f);
        *(float2*)(out + (size_t)node * 128 + lane * 2) = make_float2(ax, ay);
    } else {
        float a = 0.f;
        int i = beg;
        for (; i + 1 < end; i += 2) {
            int s0 = csr_src[i];
            int s1 = csr_src[i + 1];
            float w0 = dinv[s0] * dn;
            float w1 = dinv[s1] * dn;
            a += h[(size_t)s0 * 64 + lane] * w0 + h[(size_t)s1 * 64 + lane] * w1;
        }
        if (i < end) {
            int s = csr_src[i];
            a += h[(size_t)s * 64 + lane] * dinv[s] * dn;
        }
        a += h[(size_t)node * 64 + lane] * dn * dn + bias[lane];
        out[(size_t)node * 64 + lane] = fmaxf(a, 0.f);
    }
}

// ---------------- wave-tile fp32 GEMM ----------------
// C[M,N] = A[M,K] @ B[K,N] (+bias). 256 threads = 4 waves arranged WR x WC,
// each wave owns a 64x64 tile. Lane l = (l%8, l/8); each lane computes four
// 4x4 blocks at (+0/+32, +0/+32). All inner-loop LDS reads are aligned
// ds_read_b128, conflict-free: 8 distinct addresses x 8-lane broadcast,
// spanning all 32 banks. K must be a multiple of BK, BK multiple of BROWS.

__device__ __forceinline__ void fma4(float4& c, float a, const float4& b) {
    c.x = fmaf(a, b.x, c.x);
    c.y = fmaf(a, b.y, c.y);
    c.z = fmaf(a, b.z, c.z);
    c.w = fmaf(a, b.w, c.w);
}

template<int WR, int WC, int BK>
__launch_bounds__(256)
__global__ void gemm_wt(const float* __restrict__ A, const float* __restrict__ B,
                        const float* __restrict__ bias, float* __restrict__ C,
                        int M, int N, int K)
{
    constexpr int BM = WR * 64;
    constexpr int BN = WC * 64;
    constexpr int LDA = BM + 4;            // +4 keeps 16B alignment, stays conflict-free
    __shared__ float As[BK * LDA];         // As[k][m]
    __shared__ float Bs[BK * BN];          // Bs[k][n]

    const int tid  = threadIdx.x;
    const int wave = tid >> 6, lane = tid & 63;
    const int wr = wave / WC, wc = wave % WC;
    const int ar = wr * 64 + (lane & 7) * 4;    // row base (+32 for i=1)
    const int bc = wc * 64 + (lane >> 3) * 4;   // col base (+32 for j=1)
    const int m0 = blockIdx.x * BM;
    const int n0 = blockIdx.y * BN;

    float4 acc[2][2][4];
#pragma unroll
    for (int i = 0; i < 2; ++i)
#pragma unroll
        for (int j = 0; j < 2; ++j)
#pragma unroll
            for (int r = 0; r < 4; ++r) acc[i][j][r] = make_float4(0.f, 0.f, 0.f, 0.f);

    const int a_c4 = tid & 7;              // k-quad within BK=32 (8 slots)
    const int a_m  = tid >> 3;             // 0..31
    constexpr int BC4   = BN / 4;
    constexpr int BROWS = 256 / BC4;
    const int b_c4 = tid & (BC4 - 1);
    const int b_r  = tid / BC4;

    for (int k0 = 0; k0 < K; k0 += BK) {
        // ---- stage A tile transposed: As[k][m] = A[m0+m][k0+k] ----
#pragma unroll
        for (int p = 0; p < BM / 32; ++p) {
            int m = a_m + p * 32;
            int gr = m0 + m;
            float4 v = make_float4(0.f, 0.f, 0.f, 0.f);
            if (gr < M) v = *(const float4*)(A + (size_t)gr * K + k0 + 4 * a_c4);
            As[(4 * a_c4 + 0) * LDA + m] = v.x;
            As[(4 * a_c4 + 1) * LDA + m] = v.y;
            As[(4 * a_c4 + 2) * LDA + m] = v.z;
            As[(4 * a_c4 + 3) * LDA + m] = v.w;
        }
        // ---- stage B tile ----
#pragma unroll
        for (int p = 0; p < BK / BROWS; ++p) {
            int r = b_r + p * BROWS;
            int gc = n0 + 4 * b_c4;
            const float* Brow = B + (size_t)(k0 + r) * N;
            float4 v = make_float4(0.f, 0.f, 0.f, 0.f);
            if (gc + 3 < N) {
                v = *(const float4*)(Brow + gc);
            } else {
                if (gc + 0 < N) v.x = Brow[gc + 0];
                if (gc + 1 < N) v.y = Brow[gc + 1];
                if (gc + 2 < N) v.z = Brow[gc + 2];
            }
            *(float4*)&Bs[r * BN + 4 * b_c4] = v;
        }
        __syncthreads();

#pragma unroll
        for (int kk = 0; kk < BK; ++kk) {
            const float* as = &As[kk * LDA];
            const float* bs = &Bs[kk * BN];
            float4 a0 = *(const float4*)(as + ar);
            float4 a1 = *(const float4*)(as + ar + 32);
            float4 b0 = *(const float4*)(bs + bc);
            float4 b1 = *(const float4*)(bs + bc + 32);
            float ae0[4] = {a0.x, a0.y, a0.z, a0.w};
            float ae1[4] = {a1.x, a1.y, a1.z, a1.w};
#pragma unroll
            for (int r = 0; r < 4; ++r) {
                fma4(acc[0][0][r], ae0[r], b0);
                fma4(acc[0][1][r], ae0[r], b1);
                fma4(acc[1][0][r], ae1[r], b0);
                fma4(acc[1][1][r], ae1[r], b1);
            }
        }
        __syncthreads();
    }

    // ---- epilogue ----
#pragma unroll
    for (int i = 0; i < 2; ++i)
#pragma unroll
        for (int r = 0; r < 4; ++r) {
            int gr = m0 + ar + 32 * i + r;
            if (gr >= M) continue;
#pragma unroll
            for (int j = 0; j < 2; ++j) {
                int gc = n0 + bc + 32 * j;
                float4 v = acc[i][j][r];
                if (gc + 3 < N) {
                    if (bias) {
                        v.x += bias[gc + 0];
                        v.y += bias[gc + 1];
                        v.z += bias[gc + 2];
                        v.w += bias[gc + 3];
                    }
                    *(float4*)(C + (size_t)gr * N + gc) = v;
                } else {
                    float vv[4] = {v.x, v.y, v.z, v.w};
#pragma unroll
                    for (int e = 0; e < 4; ++e)
                        if (gc + e < N)
                            C[(size_t)gr * N + gc + e] = vv[e] + (bias ? bias[gc + e] : 0.f);
                }
            }
        }
}

// ---------------- launch ----------------
// Harness passes integer inputs as int32. d_out (400 MB) doubles as scratch:
//   O0 h[N,128] | O1 h1[N,128] | O2 h2pre[N,64] | csr_src[E] | offs[N]
//   cursor[N] | deg_cnt[N] | bsums[128]          (all dead before final GEMM)
// d_ws: [dinv 0.5MB][h2 25.6MB] — h2 must survive the final GEMM's d_out writes.

extern "C" void kernel_launch(void* const* d_in, const int* in_sizes, int n_in,
                              void* d_out, int out_size, void* d_ws, size_t ws_size,
                              hipStream_t stream)
{
    const float* x   = (const float*)d_in[0];
    const float* W1  = (const float*)d_in[1];
    const float* b1  = (const float*)d_in[2];
    const float* W2  = (const float*)d_in[3];
    const float* b2  = (const float*)d_in[4];
    const float* Wfc = (const float*)d_in[5];
    const float* bfc = (const float*)d_in[6];
    const int*   ei  = (const int*)d_in[7];     // int32 in the harness

    const int Nn = in_sizes[0] / 128;      // 100000 nodes
    const int E  = in_sizes[7] / 2;        // 1600000 edges
    const int* src = ei;
    const int* dst = ei + E;

    char* ws = (char*)d_ws;
    float* dinv = (float*)(ws);                        // Nn floats
    float* h2   = (float*)(ws + 512 * 1024);           // Nn*64 floats (25.6 MB)

    float* out = (float*)d_out;
    float* O0      = out;                              // h [Nn,128]
    float* O1      = out + (size_t)Nn * 128;           // h1 [Nn,128]
    float* O2      = out + (size_t)Nn * 256;           // h2pre [Nn,64]
    int*   csr_src = (int*)(out + (size_t)Nn * 320);   // E ints
    int*   offs    = (int*)((char*)csr_src + (size_t)E * 4);
    int*   cursor  = (int*)((char*)offs + (size_t)Nn * 4);
    int*   deg_cnt = (int*)((char*)cursor + (size_t)Nn * 4);
    int*   bsums   = (int*)((char*)deg_cnt + (size_t)Nn * 4);

    const int nScanBlocks = (Nn + SCAN_B - 1) / SCAN_B;   // 98 <= 128

    // ---- degree, dinv, offsets, cursor ----
    k_zero_i<<<128, 256, 0, stream>>>(deg_cnt, Nn);
    k_deg_i<<<(E + 255) / 256, 256, 0, stream>>>(dst, deg_cnt, E);
    k_dinv<<<(Nn + 255) / 256, 256, 0, stream>>>(deg_cnt, dinv, Nn);
    k_scan1<<<nScanBlocks, SCAN_B, 0, stream>>>(deg_cnt, offs, bsums, Nn);
    k_scan2<<<1, 128, 0, stream>>>(bsums, nScanBlocks);
    k_scan3<<<nScanBlocks, SCAN_B, 0, stream>>>(offs, cursor, bsums, Nn);

    // ---- CSR fill ----
    k_fill<<<(E + 255) / 256, 256, 0, stream>>>(src, dst, cursor, csr_src, E);

    // ---- layer 1 ----
    // h = x @ W1 -> O0
    gemm_wt<2, 2, 32><<<dim3((Nn + 127) / 128, 1), 256, 0, stream>>>(
        x, W1, nullptr, O0, Nn, 128, 128);
    // h1 = relu(gather(h) + self + b1) -> O1
    k_gather<128><<<(Nn + 3) / 4, 256, 0, stream>>>(O0, csr_src, offs, dinv, b1, O1, Nn, E);

    // ---- layer 2 ----
    // h2pre = h1 @ W2 -> O2
    gemm_wt<4, 1, 32><<<dim3((Nn + 255) / 256, 1), 256, 0, stream>>>(
        O1, W2, nullptr, O2, Nn, 64, 128);
    // h2 = relu(gather(h2pre) + self + b2) -> ws
    k_gather<64><<<(Nn + 3) / 4, 256, 0, stream>>>(O2, csr_src, offs, dinv, b2, h2, Nn, E);

    // ---- output layer: out = h2 @ Wfc + bfc (overwrites all of d_out) ----
    gemm_wt<2, 2, 32><<<dim3((Nn + 127) / 128, (1000 + 127) / 128), 256, 0, stream>>>(
        h2, Wfc, bfc, out, Nn, 1000, 64);
}